// Round 5
// baseline (594.835 us; speedup 1.0000x reference)
//
#include <hip/hip_runtime.h>
#include <stdint.h>

// Problem constants (fixed by reference setup_inputs)
#define TOKENS 4096
#define HIDDEN 4096   // K
#define NQ     4096
#define NKV    1024
#define NTOT   6144   // NQ + 2*NKV
#define KPACK  512    // HIDDEN / 8
#define MAXTILES 20   // max sum_d ceil(cnt_d/256) = 16 + 4

typedef __attribute__((ext_vector_type(8))) __bf16 bf16x8;
typedef __attribute__((ext_vector_type(8))) short short8v;
typedef __attribute__((ext_vector_type(4))) float floatx4;

// fp32 -> bf16 round-to-nearest-even (finite inputs only)
__device__ __forceinline__ short f2bf(float f) {
  union { float f; unsigned u; } v; v.f = f;
  unsigned r = v.u + 0x7fffu + ((v.u >> 16) & 1u);
  return (short)(r >> 16);
}

// async global->LDS, 16B per lane; LDS dest = wave-uniform base + lane*16
__device__ __forceinline__ void load_lds16(const void* g, void* l) {
  __builtin_amdgcn_global_load_lds((__attribute__((address_space(1))) void*)(g),
                                   (__attribute__((address_space(3))) void*)(l),
                                   16, 0, 0);
}

// ---------------------------------------------------------------------------
// Kernel 1: bucket tokens by delta index + build compact tile table.
// grp[0..3]=start, grp[4..7]=count, grp[8]=n_tiles, grp[9..9+nt)=d|(rt<<2).
// Row tiles are 256 tokens (BM=256 in the GEMM).
// ---------------------------------------------------------------------------
__global__ __launch_bounds__(256) void prep_tokens(const int* __restrict__ idx,
                                                   int* __restrict__ token_list,
                                                   int* __restrict__ grp) {
  __shared__ int cnt[4], cur[4];
  const int tid = threadIdx.x;
  if (tid < 4) cnt[tid] = 0;
  __syncthreads();
  for (int t = tid; t < TOKENS; t += 256) {
    int d = idx[t];
    if ((unsigned)d < 4u) atomicAdd(&cnt[d], 1);
  }
  __syncthreads();
  if (tid == 0) {
    int s = 0, nt = 0;
    for (int d = 0; d < 4; d++) {
      cur[d] = s; grp[d] = s; grp[4 + d] = cnt[d]; s += cnt[d];
      int tiles = (cnt[d] + 255) >> 8;
      for (int rt = 0; rt < tiles; rt++) grp[9 + nt++] = d | (rt << 2);
    }
    grp[8] = nt;
  }
  __syncthreads();
  for (int t = tid; t < TOKENS; t += 256) {
    int d = idx[t];
    if ((unsigned)d < 4u) {
      int p = atomicAdd(&cur[d], 1);
      token_list[p] = t;
    }
  }
}

// ---------------------------------------------------------------------------
// Kernel 2: x fp32 -> bf16 (row-major (TOKENS, HIDDEN)); 8 elems/thread.
// ---------------------------------------------------------------------------
__global__ __launch_bounds__(256) void cvt_x(const float* __restrict__ x,
                                             short* __restrict__ xb) {
  size_t g = (size_t)blockIdx.x * 256 + threadIdx.x;
  size_t i = g * 8;
  float4 a = ((const float4*)(x + i))[0];
  float4 b = ((const float4*)(x + i))[1];
  short8v o;
  o[0] = f2bf(a.x); o[1] = f2bf(a.y); o[2] = f2bf(a.z); o[3] = f2bf(a.w);
  o[4] = f2bf(b.x); o[5] = f2bf(b.y); o[6] = f2bf(b.z); o[7] = f2bf(b.w);
  *(short8v*)(xb + i) = o;
}

// ---------------------------------------------------------------------------
// Kernel 3: Wc[d] (NTOT x HIDDEN bf16, B^T layout) = base + dequant(delta_d).
// (unchanged — will read its counters once GEMM stops dominating top-5)
// ---------------------------------------------------------------------------
__global__ __launch_bounds__(256) void combine_w(
    const float* __restrict__ bw,
    const int* __restrict__ qwq, const int* __restrict__ qwk, const int* __restrict__ qwv,
    const int* __restrict__ qzq, const int* __restrict__ qzk, const int* __restrict__ qzv,
    const float* __restrict__ scq, const float* __restrict__ sck, const float* __restrict__ scv,
    short* __restrict__ wc) {
  __shared__ int ldsq[4][8][72];
  __shared__ float zs[4][64], ss[4][64];
  const int tid = threadIdx.x;
  const int n0  = blockIdx.y * 64;
  const int kp0 = blockIdx.x * 8;   // k0 = kp0*8

  const int* qw; const int* qz; const float* sc; int Ns, nb;
  if (n0 < NQ)            { qw = qwq; qz = qzq; sc = scq; Ns = NQ;  nb = n0; }
  else if (n0 < NQ + NKV) { qw = qwk; qz = qzk; sc = sck; Ns = NKV; nb = n0 - NQ; }
  else                    { qw = qwv; qz = qzv; sc = scv; Ns = NKV; nb = n0 - NQ - NKV; }

  // zeros + scales: tid -> (d = tid>>6, n = tid&63)
  {
    int d = tid >> 6, n = tid & 63;
    int nn = nb + n;
    int z = (int)(((unsigned)qz[d * (Ns >> 3) + (nn >> 3)] >> ((nn & 7) * 4)) & 0xFu);
    zs[d][n] = (float)(z + 1);
    ss[d][n] = sc[d * Ns + nn];
  }

  // phase A: stage raw ints (coalesced along n; conflict-free LDS writes)
#pragma unroll
  for (int d = 0; d < 4; d++) {
#pragma unroll
    for (int p = 0; p < 2; p++) {
      int i  = tid + p * 256;
      int kp = i >> 6, n = i & 63;
      ldsq[d][kp][n] = qw[((size_t)d * KPACK + kp0 + kp) * Ns + nb + n];
    }
  }
  __syncthreads();

  // phase B: lane -> (kp = tid&7, n = tid>>3 + p*32); base once, d innermost
  const int kp = tid & 7;
#pragma unroll
  for (int p = 0; p < 2; p++) {
    int n = (tid >> 3) + p * 32;
    const float4* bp = (const float4*)(bw + (size_t)(n0 + n) * HIDDEN + (kp0 + kp) * 8);
    float4 b0 = bp[0], b1 = bp[1];
    float bv[8] = {b0.x, b0.y, b0.z, b0.w, b1.x, b1.y, b1.z, b1.w};
#pragma unroll
    for (int d = 0; d < 4; d++) {
      unsigned q32 = (unsigned)ldsq[d][kp][n];
      float z = zs[d][n], s = ss[d][n];
      short8v o;
#pragma unroll
      for (int j = 0; j < 8; j++)
        o[j] = f2bf(((float)((q32 >> (4 * j)) & 0xFu) - z) * s + bv[j]);
      *(short8v*)(wc + ((size_t)d * NTOT + n0 + n) * HIDDEN + (kp0 + kp) * 8) = o;
    }
  }
}

// ---------------------------------------------------------------------------
// Kernel 4: grouped gathered GEMM. out[tok] = xb[tok] @ Wc[d]^T
//
// v4 (3rd submission; rounds 3+4 were container-acquisition failures, no
// counters; hang-audit in journal: uniform barriers, live waitcnts,
// in-bounds staging — kernel cannot hang/fault): 256x256 tile, 512 thr /
// 8 waves (2Mx4N -> 128x64/wave), BK=32, ring-4 LDS (128 KB), counted
// vmcnt, PLUS register-level fragment double-buffer:
//   iter t: stage(t+3) ; s_waitcnt vmcnt(8) lgkmcnt(0) ; s_barrier ;
//           sched_barrier ;
//           ds_reads(tile t+1 -> fragset (t+1)&1) || 32 MFMA(tile t)
// Reads and MFMA share a scheduling region with no register dependence,
// so read issue+latency hides under the MFMA cluster; the consuming MFMA
// is one barrier window later. (v3 pinned reads AFTER the barrier and
// MFMA AFTER the reads -> exposed the full read head per K-tile,
// MfmaUtil 35%.)
//
// Hazards: RAW-global: after stage(t+3), outstanding <= 12; vmcnt(8) =>
// tile t+1 landed; barrier makes it cross-wave => reads(t+1) safe.
// WAR: stage(t+4) overwrites ring[t&3], last read by reads(t) at iter t-1;
// every wave's lgkmcnt(0) precedes BAR#t and stage(t+4) follows BAR#t.
// RAW-regs: compiler-tracked ds_read->VGPR deps insert lgkm waits.
// ---------------------------------------------------------------------------
struct Frags { bf16x8 a[8]; bf16x8 b[4]; };

__device__ __forceinline__ void stage_t(int t, short* aBuf, short* bBuf,
                                        const short* gA0, const short* gA1,
                                        const short* gB0, const short* gB1,
                                        int wave) {
  const int ko = t * 32;               // k offset in shorts
  short* la = aBuf + wave * 512;       // + lane*16B implicit
  short* lb = bBuf + wave * 512;
  load_lds16(gA0 + ko, la);
  load_lds16(gA1 + ko, la + 4096);
  load_lds16(gB0 + ko, lb);
  load_lds16(gB1 + ko, lb + 4096);
}

__device__ __forceinline__ void lds_reads(const short* Ab, const short* Bb,
                                          int wm, int wn, int mrow, int sx,
                                          Frags& f) {
#pragma unroll
  for (int j = 0; j < 4; j++)
    f.b[j] = *(const bf16x8*)(Bb + (wn * 64 + j * 16 + mrow) * 32 + sx);
#pragma unroll
  for (int i = 0; i < 8; i++)
    f.a[i] = *(const bf16x8*)(Ab + (wm * 128 + i * 16 + mrow) * 32 + sx);
}

__device__ __forceinline__ void mfma_tile(const Frags& f, floatx4 acc[8][4]) {
  __builtin_amdgcn_s_setprio(1);
#pragma unroll
  for (int i = 0; i < 8; i++)
#pragma unroll
    for (int j = 0; j < 4; j++)
      acc[i][j] = __builtin_amdgcn_mfma_f32_16x16x32_bf16(f.a[i], f.b[j], acc[i][j], 0, 0, 0);
  __builtin_amdgcn_s_setprio(0);
}

// iter t: stage tile TNXT=t+3 into ring[SN]; read tile t+1 from ring[RN]
// into fr[FN]; MFMA tile t from fr[FC].  All indices compile-time via x4
// unroll (rule #20: static frag indexing).
#define GSTEP4(TNXT, SN, RN, FC, FN)                                        \
  stage_t(TNXT, &As[SN][0], &Bs[SN][0], gA0, gA1, gB0, gB1, wave);          \
  asm volatile("s_waitcnt vmcnt(8) lgkmcnt(0)" ::: "memory");               \
  __builtin_amdgcn_s_barrier();                                             \
  __builtin_amdgcn_sched_barrier(0);                                        \
  lds_reads(&As[RN][0], &Bs[RN][0], wm, wn, mrow, sx, fr[FN]);              \
  mfma_tile(fr[FC], acc);

__global__ __launch_bounds__(512, 2) void gemm_grouped(
    const short* __restrict__ xb, const short* __restrict__ wc,
    const int* __restrict__ token_list, const int* __restrict__ grp,
    float* __restrict__ out) {
  const int nt = grp[8];
  if ((int)blockIdx.y >= nt) return;
  const int te = grp[9 + blockIdx.y];
  const int d  = te & 3;
  const int rt = te >> 2;
  const int cnt   = grp[4 + d];
  const int start = grp[d];
  const int n0 = blockIdx.x * 256;

  // ring-4 K-tile buffers: 4 x (A 16KB + B 16KB) = 128 KB
  __shared__ __align__(16) short As[4][8192];
  __shared__ __align__(16) short Bs[4][8192];
  __shared__ int toks[256];

  const int tid = threadIdx.x;
  if (tid < 256) {
    int r = rt * 256 + tid;
    if (r >= cnt) r = cnt - 1;          // clamp tail (stores guarded below)
    toks[tid] = token_list[start + r];
  }
  __syncthreads();

  const int wave = tid >> 6;
  const int lane = tid & 63;

  // staging unit u (16B) holds global (row = u>>2, seg = (u&3)^((u>>3)&3));
  // per-lane seg swizzle (chunk offsets are multiples of 64 units):
  const int sw = ((lane & 3) ^ ((lane >> 3) & 3)) * 8;  // shorts

  const int arow = wave * 16 + (lane >> 2);
  const short* gA0 = xb + (size_t)toks[arow] * HIDDEN + sw;
  const short* gA1 = xb + (size_t)toks[arow + 128] * HIDDEN + sw;
  const short* wrow = wc + ((size_t)d * NTOT + n0) * HIDDEN;
  const short* gB0 = wrow + (size_t)arow * HIDDEN + sw;
  const short* gB1 = gB0 + (size_t)128 * HIDDEN;

  const int mrow = lane & 15;
  // fragment read: (row r, kseg s) lives at unit r*4 + (s^((r>>1)&3));
  // row bases are multiples of 16 -> (r>>1)&3 == (mrow>>1)&3
  const int sx = (((lane >> 4) ^ ((mrow >> 1) & 3))) * 8;
  const int wm = wave >> 2;   // 0..1  (M half)
  const int wn = wave & 3;    // 0..3  (N quarter)

  floatx4 acc[8][4];
#pragma unroll
  for (int i = 0; i < 8; i++)
#pragma unroll
    for (int j = 0; j < 4; j++) acc[i][j] = (floatx4){0.f, 0.f, 0.f, 0.f};

  Frags fr[2];

  // prologue: stage tiles 0..2 (12 loads in flight); tile 0 landed at vmcnt(8)
  stage_t(0, &As[0][0], &Bs[0][0], gA0, gA1, gB0, gB1, wave);
  stage_t(1, &As[1][0], &Bs[1][0], gA0, gA1, gB0, gB1, wave);
  stage_t(2, &As[2][0], &Bs[2][0], gA0, gA1, gB0, gB1, wave);
  asm volatile("s_waitcnt vmcnt(8)" ::: "memory");
  __builtin_amdgcn_s_barrier();
  __builtin_amdgcn_sched_barrier(0);
  lds_reads(&As[0][0], &Bs[0][0], wm, wn, mrow, sx, fr[0]);   // reads(0)

  // main loop: t = 0..123 (stages tiles 3..126)
  for (int it = 0; it < 31; ++it) {
    const int t = it * 4;
    GSTEP4(t + 3, 3, 1, 0, 1);   // t+0: mfma(t),   reads(t+1)
    GSTEP4(t + 4, 0, 2, 1, 0);   // t+1
    GSTEP4(t + 5, 1, 3, 0, 1);   // t+2
    GSTEP4(t + 6, 2, 0, 1, 0);   // t+3
  }
  // t=124: stage(127)
  GSTEP4(127, 3, 1, 0, 1);
  // t=125: no stage; outstanding {126,127}=8 -> vmcnt(4) => 126 landed
  asm volatile("s_waitcnt vmcnt(4) lgkmcnt(0)" ::: "memory");
  __builtin_amdgcn_s_barrier();
  __builtin_amdgcn_sched_barrier(0);
  lds_reads(&As[2][0], &Bs[2][0], wm, wn, mrow, sx, fr[0]);   // reads(126)
  mfma_tile(fr[1], acc);                                      // mfma(125)
  // t=126: vmcnt(0) => 127 landed
  asm volatile("s_waitcnt vmcnt(0) lgkmcnt(0)" ::: "memory");
  __builtin_amdgcn_s_barrier();
  __builtin_amdgcn_sched_barrier(0);
  lds_reads(&As[3][0], &Bs[3][0], wm, wn, mrow, sx, fr[1]);   // reads(127)
  mfma_tile(fr[0], acc);                                      // mfma(126)
  // t=127 (compiler inserts the lgkm wait from register deps)
  mfma_tile(fr[1], acc);                                      // mfma(127)

  // epilogue: C/D layout col = lane&15, row = (lane>>4)*4 + reg
  const int rbase = (lane >> 4) * 4;
  const int coll  = lane & 15;
#pragma unroll
  for (int i = 0; i < 8; i++) {
#pragma unroll
    for (int r = 0; r < 4; r++) {
      int m = wm * 128 + i * 16 + rbase + r;
      if (rt * 256 + m < cnt) {
        float* orow = out + (size_t)toks[m] * NTOT + n0 + wn * 64 + coll;
#pragma unroll
        for (int j = 0; j < 4; j++) orow[j * 16] = acc[i][j][r];
      }
    }
  }
}

// ---------------------------------------------------------------------------
extern "C" void kernel_launch(void* const* d_in, const int* in_sizes, int n_in,
                              void* d_out, int out_size, void* d_ws, size_t ws_size,
                              hipStream_t stream) {
  const float* x   = (const float*)d_in[0];
  const float* bw  = (const float*)d_in[1];
  const int*   qwq = (const int*)d_in[2];
  const int*   qwk = (const int*)d_in[3];
  const int*   qwv = (const int*)d_in[4];
  const int*   qzq = (const int*)d_in[5];
  const int*   qzk = (const int*)d_in[6];
  const int*   qzv = (const int*)d_in[7];
  const float* scq = (const float*)d_in[8];
  const float* sck = (const float*)d_in[9];
  const float* scv = (const float*)d_in[10];
  const int*   idx = (const int*)d_in[11];
  float* out = (float*)d_out;

  // workspace layout (needs ~235 MB)
  char* ws = (char*)d_ws;
  short* xb = (short*)ws;                                       // 33,554,432 B
  short* wc = (short*)(ws + (size_t)33554432);                  // 201,326,592 B
  int* token_list = (int*)(ws + (size_t)33554432 + 201326592);  // 16,384 B
  int* grp = token_list + TOKENS;                               // 256 B

  prep_tokens<<<1, 256, 0, stream>>>(idx, token_list, grp);
  cvt_x<<<(TOKENS * HIDDEN) / (256 * 8), 256, 0, stream>>>(x, xb);
  dim3 gc(HIDDEN / 64, NTOT / 64);  // (64, 96)
  combine_w<<<gc, 256, 0, stream>>>(bw, qwq, qwk, qwv, qzq, qzk, qzv, scq, sck, scv, wc);
  dim3 gg(NTOT / 256, MAXTILES);  // (24, 20)
  gemm_grouped<<<gg, 512, 0, stream>>>(xb, wc, token_list, grp, out);
}

// Round 7
// 572.113 us; speedup vs baseline: 1.0397x; 1.0397x over previous
//
#include <hip/hip_runtime.h>
#include <stdint.h>

// Problem constants (fixed by reference setup_inputs)
#define TOKENS 4096
#define HIDDEN 4096   // K
#define NQ     4096
#define NKV    1024
#define NTOT   6144   // NQ + 2*NKV
#define KPACK  512    // HIDDEN / 8
#define MAXTILES 20   // max sum_d ceil(cnt_d/256) = 16 + 4

typedef __attribute__((ext_vector_type(8))) __bf16 bf16x8;
typedef __attribute__((ext_vector_type(8))) short short8v;
typedef __attribute__((ext_vector_type(4))) float floatx4;

// fp32 -> bf16 round-to-nearest-even (finite inputs only)
__device__ __forceinline__ short f2bf(float f) {
  union { float f; unsigned u; } v; v.f = f;
  unsigned r = v.u + 0x7fffu + ((v.u >> 16) & 1u);
  return (short)(r >> 16);
}

// async global->LDS, 16B per lane; LDS dest = wave-uniform base + lane*16
__device__ __forceinline__ void load_lds16(const void* g, void* l) {
  __builtin_amdgcn_global_load_lds((__attribute__((address_space(1))) void*)(g),
                                   (__attribute__((address_space(3))) void*)(l),
                                   16, 0, 0);
}

// ---------------------------------------------------------------------------
// Kernel 1: bucket tokens by delta index + build compact tile table.
// grp[0..3]=start, grp[4..7]=count, grp[8]=n_tiles, grp[9..9+nt)=d|(rt<<2).
// Row tiles are 256 tokens (BM=256 in the GEMM).
// ---------------------------------------------------------------------------
__global__ __launch_bounds__(256) void prep_tokens(const int* __restrict__ idx,
                                                   int* __restrict__ token_list,
                                                   int* __restrict__ grp) {
  __shared__ int cnt[4], cur[4];
  const int tid = threadIdx.x;
  if (tid < 4) cnt[tid] = 0;
  __syncthreads();
  for (int t = tid; t < TOKENS; t += 256) {
    int d = idx[t];
    if ((unsigned)d < 4u) atomicAdd(&cnt[d], 1);
  }
  __syncthreads();
  if (tid == 0) {
    int s = 0, nt = 0;
    for (int d = 0; d < 4; d++) {
      cur[d] = s; grp[d] = s; grp[4 + d] = cnt[d]; s += cnt[d];
      int tiles = (cnt[d] + 255) >> 8;
      for (int rt = 0; rt < tiles; rt++) grp[9 + nt++] = d | (rt << 2);
    }
    grp[8] = nt;
  }
  __syncthreads();
  for (int t = tid; t < TOKENS; t += 256) {
    int d = idx[t];
    if ((unsigned)d < 4u) {
      int p = atomicAdd(&cur[d], 1);
      token_list[p] = t;
    }
  }
}

// ---------------------------------------------------------------------------
// Kernel 2: x fp32 -> bf16 (row-major (TOKENS, HIDDEN)); 8 elems/thread.
// ---------------------------------------------------------------------------
__global__ __launch_bounds__(256) void cvt_x(const float* __restrict__ x,
                                             short* __restrict__ xb) {
  size_t g = (size_t)blockIdx.x * 256 + threadIdx.x;
  size_t i = g * 8;
  float4 a = ((const float4*)(x + i))[0];
  float4 b = ((const float4*)(x + i))[1];
  short8v o;
  o[0] = f2bf(a.x); o[1] = f2bf(a.y); o[2] = f2bf(a.z); o[3] = f2bf(a.w);
  o[4] = f2bf(b.x); o[5] = f2bf(b.y); o[6] = f2bf(b.z); o[7] = f2bf(b.w);
  *(short8v*)(xb + i) = o;
}

// ---------------------------------------------------------------------------
// Kernel 3: Wc[d] (NTOT x HIDDEN bf16, B^T layout) = base + dequant(delta_d).
// (unchanged — will attack with counters once GEMM stops dominating top-5)
// ---------------------------------------------------------------------------
__global__ __launch_bounds__(256) void combine_w(
    const float* __restrict__ bw,
    const int* __restrict__ qwq, const int* __restrict__ qwk, const int* __restrict__ qwv,
    const int* __restrict__ qzq, const int* __restrict__ qzk, const int* __restrict__ qzv,
    const float* __restrict__ scq, const float* __restrict__ sck, const float* __restrict__ scv,
    short* __restrict__ wc) {
  __shared__ int ldsq[4][8][72];
  __shared__ float zs[4][64], ss[4][64];
  const int tid = threadIdx.x;
  const int n0  = blockIdx.y * 64;
  const int kp0 = blockIdx.x * 8;   // k0 = kp0*8

  const int* qw; const int* qz; const float* sc; int Ns, nb;
  if (n0 < NQ)            { qw = qwq; qz = qzq; sc = scq; Ns = NQ;  nb = n0; }
  else if (n0 < NQ + NKV) { qw = qwk; qz = qzk; sc = sck; Ns = NKV; nb = n0 - NQ; }
  else                    { qw = qwv; qz = qzv; sc = scv; Ns = NKV; nb = n0 - NQ - NKV; }

  // zeros + scales: tid -> (d = tid>>6, n = tid&63)
  {
    int d = tid >> 6, n = tid & 63;
    int nn = nb + n;
    int z = (int)(((unsigned)qz[d * (Ns >> 3) + (nn >> 3)] >> ((nn & 7) * 4)) & 0xFu);
    zs[d][n] = (float)(z + 1);
    ss[d][n] = sc[d * Ns + nn];
  }

  // phase A: stage raw ints (coalesced along n; conflict-free LDS writes)
#pragma unroll
  for (int d = 0; d < 4; d++) {
#pragma unroll
    for (int p = 0; p < 2; p++) {
      int i  = tid + p * 256;
      int kp = i >> 6, n = i & 63;
      ldsq[d][kp][n] = qw[((size_t)d * KPACK + kp0 + kp) * Ns + nb + n];
    }
  }
  __syncthreads();

  // phase B: lane -> (kp = tid&7, n = tid>>3 + p*32); base once, d innermost
  const int kp = tid & 7;
#pragma unroll
  for (int p = 0; p < 2; p++) {
    int n = (tid >> 3) + p * 32;
    const float4* bp = (const float4*)(bw + (size_t)(n0 + n) * HIDDEN + (kp0 + kp) * 8);
    float4 b0 = bp[0], b1 = bp[1];
    float bv[8] = {b0.x, b0.y, b0.z, b0.w, b1.x, b1.y, b1.z, b1.w};
#pragma unroll
    for (int d = 0; d < 4; d++) {
      unsigned q32 = (unsigned)ldsq[d][kp][n];
      float z = zs[d][n], s = ss[d][n];
      short8v o;
#pragma unroll
      for (int j = 0; j < 8; j++)
        o[j] = f2bf(((float)((q32 >> (4 * j)) & 0xFu) - z) * s + bv[j]);
      *(short8v*)(wc + ((size_t)d * NTOT + n0 + n) * HIDDEN + (kp0 + kp) * 8) = o;
    }
  }
}

// ---------------------------------------------------------------------------
// Kernel 4: grouped gathered GEMM. out[tok] = xb[tok] @ Wc[d]^T
//
// v5 (2nd submission — round 6 was a container-acquisition failure; the
// round-5 success of an identically-resubmitted v4 proves the harness
// fails ~50% regardless of kernel content; full vmcnt/WAR/barrier ledger
// re-audited, no hang surface) = faithful port of the m201 8-phase
// template. v0/v3/v4's coarse read-block+MFMA-block schedules all
// plateaued at 285-315 us / 30-35% MfmaUtil — m196's "coarse phase-split
// without fine interleave" failure mode.
//
// Geometry: 256x256 tile, 512 thr / 8 waves (2Mx4N -> 128x64/wave).
// K-tile BK=64 split into two 32-K halves (kh0/kh1); LDS = 2 dbuf x
// {A,B} x {kh0,kh1} x [256 rows x 32 K] 16KB buffers = 128 KB. Each
// half-buffer is geometry-identical to the verified v0-v4 staging tile:
// unit u(16B) holds (row u>>2, seg (u&3)^((u>>3)&3)); stage source
// pre-swizzled by sw, fragment reads via sx — measured 0 bank conflicts.
//
// Per iteration (2 K-tiles: T=2i in buf0, T+1 in buf1), 8 phases:
//  odd  ph: 8 ds_read (B-frags j0-3 + A-frags m0-3 of one kh) ;
//           stage A-half ; bar ; lgkmcnt(0) ; 16 MFMA (m0-3) ; bar
//  even ph: 4 ds_read (A-frags m4-7, B reused) ; stage B-half ;
//           s_waitcnt vmcnt(4) ; bar ; lgkmcnt(0) ; 16 MFMA (m4-7) ; bar
// Stage stream: ph1-4 -> tile T+1 (buf1), ph5-8 -> tile T+2 (buf0).
// vmcnt(4) at even phases: outstanding is exactly 8 there; the 4 waited
// loads are exactly the half-tile read two phases later. Never vmcnt(0)
// in the main loop. WAR: every overwrite is >=1 full barrier after the
// last read's lgkmcnt(0) (ledger in journal, all 8 targets checked).
// Prologue: stage tile0 (8 loads), vmcnt(4), barrier -> steady invariant.
// Last iteration peeled: stages ph1-4 only (tile 63), vmcnt(0) at ph6.
// ---------------------------------------------------------------------------
__device__ __forceinline__ void rdB(const short* Bb, int wn, int mrow, int sx,
                                    bf16x8 bf[4]) {
#pragma unroll
  for (int j = 0; j < 4; j++)
    bf[j] = *(const bf16x8*)(Bb + (wn * 64 + j * 16 + mrow) * 32 + sx);
}
__device__ __forceinline__ void rdA(const short* Ab, int wm, int g, int mrow,
                                    int sx, bf16x8 af[4]) {
#pragma unroll
  for (int i = 0; i < 4; i++)
    af[i] = *(const bf16x8*)(Ab + (wm * 128 + (g * 4 + i) * 16 + mrow) * 32 + sx);
}
__device__ __forceinline__ void mm(const bf16x8 af[4], const bf16x8 bf[4],
                                   floatx4 acc[8][4], int g) {
  __builtin_amdgcn_s_setprio(1);
#pragma unroll
  for (int i = 0; i < 4; i++)
#pragma unroll
    for (int j = 0; j < 4; j++)
      acc[g * 4 + i][j] =
          __builtin_amdgcn_mfma_f32_16x16x32_bf16(af[i], bf[j], acc[g * 4 + i][j], 0, 0, 0);
  __builtin_amdgcn_s_setprio(0);
}
// stage one 16KB half (256 rows x 32 K) of one matrix: 2 loads/thread.
// dst must be half-buffer base + wave*1024 shorts (lane*16B implicit).
__device__ __forceinline__ void st2(short* dst, const short* g0, const short* g1,
                                    int ko) {
  load_lds16(g0 + ko, dst);
  load_lds16(g1 + ko, dst + 512);
}

#define BARRIER __builtin_amdgcn_s_barrier()
#define LGKM0 asm volatile("s_waitcnt lgkmcnt(0)" ::: "memory")
#define VMC4  asm volatile("s_waitcnt vmcnt(4)" ::: "memory")
#define VMC0  asm volatile("s_waitcnt vmcnt(0)" ::: "memory")

// odd phase: reads kh buffer (B + A m0-3), stages an A-half, computes m0-3
#define PH_O(RB, RA, SD, KO)                                   \
  rdB(RB, wn, mrow, sx, bf);                                   \
  rdA(RA, wm, 0, mrow, sx, af);                                \
  st2((SD) + wave * 1024, gA0, gA1, (KO));                     \
  BARRIER; LGKM0; mm(af, bf, acc, 0); BARRIER;
// even phase: reads A m4-7 (B reused), stages a B-half, vmcnt(4), m4-7
#define PH_E(RA, SD, KO)                                       \
  rdA(RA, wm, 1, mrow, sx, af);                                \
  st2((SD) + wave * 1024, gB0, gB1, (KO));                     \
  VMC4; BARRIER; LGKM0; mm(af, bf, acc, 1); BARRIER;

__global__ __launch_bounds__(512, 2) void gemm_grouped(
    const short* __restrict__ xb, const short* __restrict__ wc,
    const int* __restrict__ token_list, const int* __restrict__ grp,
    float* __restrict__ out) {
  const int nt = grp[8];
  if ((int)blockIdx.y >= nt) return;
  const int te = grp[9 + blockIdx.y];
  const int d  = te & 3;
  const int rt = te >> 2;
  const int cnt   = grp[4 + d];
  const int start = grp[d];
  const int n0 = blockIdx.x * 256;

  // [dbuf][kh][256 rows x 32 K] 16KB halves; total 128 KB
  __shared__ __align__(16) short Ak[2][2][8192];
  __shared__ __align__(16) short Bk[2][2][8192];
  __shared__ int toks[256];

  const int tid = threadIdx.x;
  if (tid < 256) {
    int r = rt * 256 + tid;
    if (r >= cnt) r = cnt - 1;          // clamp tail (stores guarded below)
    toks[tid] = token_list[start + r];
  }
  __syncthreads();

  const int wave = tid >> 6;
  const int lane = tid & 63;

  // stage source pre-swizzle: unit u holds seg (u&3)^((u>>3)&3); per wave
  // instr covers units w*128 + j*64 + lane -> seg = (lane&3)^((lane>>3)&3)
  const int sw = ((lane & 3) ^ ((lane >> 3) & 3)) * 8;  // shorts

  // per-lane row pointers: instr j of wave w covers rows w*32 + j*16 + (lane>>2)
  const int arow = wave * 32 + (lane >> 2);
  const short* gA0 = xb + (size_t)toks[arow] * HIDDEN + sw;
  const short* gA1 = xb + (size_t)toks[arow + 16] * HIDDEN + sw;
  const short* wrow = wc + ((size_t)d * NTOT + n0) * HIDDEN;
  const short* gB0 = wrow + (size_t)arow * HIDDEN + sw;
  const short* gB1 = gB0 + (size_t)16 * HIDDEN;

  const int mrow = lane & 15;
  // fragment read: (row r, kseg s) at unit r*4 + (s ^ ((r>>1)&3));
  // row bases are multiples of 16 -> (r>>1)&3 == (mrow>>1)&3
  const int sx = (((lane >> 4) ^ ((mrow >> 1) & 3))) * 8;
  const int wm = wave >> 2;   // 0..1  (M half)
  const int wn = wave & 3;    // 0..3  (N quarter)

  floatx4 acc[8][4];
#pragma unroll
  for (int i = 0; i < 8; i++)
#pragma unroll
    for (int j = 0; j < 4; j++) acc[i][j] = (floatx4){0.f, 0.f, 0.f, 0.f};

  bf16x8 af[4], bf[4];

  // prologue: stage tile 0 (kh0 A,B then kh1 A,B = 8 loads); vmcnt(4)
  // leaves kh1 (4 loads) in flight == steady-state iter-entry invariant.
  st2(&Ak[0][0][0] + wave * 1024, gA0, gA1, 0);
  st2(&Bk[0][0][0] + wave * 1024, gB0, gB1, 0);
  st2(&Ak[0][1][0] + wave * 1024, gA0, gA1, 32);
  st2(&Bk[0][1][0] + wave * 1024, gB0, gB1, 32);
  VMC4;
  BARRIER;

  // main loop: iter it covers tiles 2it (buf0), 2it+1 (buf1);
  // stages tile 2it+1 (ph1-4) and 2it+2 (ph5-8). Tiles 0..61 here.
  for (int it = 0; it < 31; ++it) {
    const int kb = it * 128;
    PH_O(&Bk[0][0][0], &Ak[0][0][0], &Ak[1][0][0], kb + 64);
    PH_E(&Ak[0][0][0],               &Bk[1][0][0], kb + 64);
    PH_O(&Bk[0][1][0], &Ak[0][1][0], &Ak[1][1][0], kb + 96);
    PH_E(&Ak[0][1][0],               &Bk[1][1][0], kb + 96);
    PH_O(&Bk[1][0][0], &Ak[1][0][0], &Ak[0][0][0], kb + 128);
    PH_E(&Ak[1][0][0],               &Bk[0][0][0], kb + 128);
    PH_O(&Bk[1][1][0], &Ak[1][1][0], &Ak[0][1][0], kb + 160);
    PH_E(&Ak[1][1][0],               &Bk[0][1][0], kb + 160);
  }
  // peeled last iteration: tiles 62 (buf0), 63 (buf1); stage tile 63 only.
  PH_O(&Bk[0][0][0], &Ak[0][0][0], &Ak[1][0][0], 4032);
  PH_E(&Ak[0][0][0],               &Bk[1][0][0], 4032);
  PH_O(&Bk[0][1][0], &Ak[0][1][0], &Ak[1][1][0], 4064);
  PH_E(&Ak[0][1][0],               &Bk[1][1][0], 4064);
  // ph5-8: no stages; vmcnt(0) once (tile 63 kh1) before its reads.
  rdB(&Bk[1][0][0], wn, mrow, sx, bf);
  rdA(&Ak[1][0][0], wm, 0, mrow, sx, af);
  BARRIER; LGKM0; mm(af, bf, acc, 0); BARRIER;
  rdA(&Ak[1][0][0], wm, 1, mrow, sx, af);
  VMC0; BARRIER; LGKM0; mm(af, bf, acc, 1); BARRIER;
  rdB(&Bk[1][1][0], wn, mrow, sx, bf);
  rdA(&Ak[1][1][0], wm, 0, mrow, sx, af);
  BARRIER; LGKM0; mm(af, bf, acc, 0); BARRIER;
  rdA(&Ak[1][1][0], wm, 1, mrow, sx, af);
  BARRIER; LGKM0; mm(af, bf, acc, 1);

  // epilogue: C/D layout col = lane&15, row = (lane>>4)*4 + reg
  const int rbase = (lane >> 4) * 4;
  const int coll  = lane & 15;
#pragma unroll
  for (int i = 0; i < 8; i++) {
#pragma unroll
    for (int r = 0; r < 4; r++) {
      int m = wm * 128 + i * 16 + rbase + r;
      if (rt * 256 + m < cnt) {
        float* orow = out + (size_t)toks[m] * NTOT + n0 + wn * 64 + coll;
#pragma unroll
        for (int j = 0; j < 4; j++) orow[j * 16] = acc[i][j][r];
      }
    }
  }
}

// ---------------------------------------------------------------------------
extern "C" void kernel_launch(void* const* d_in, const int* in_sizes, int n_in,
                              void* d_out, int out_size, void* d_ws, size_t ws_size,
                              hipStream_t stream) {
  const float* x   = (const float*)d_in[0];
  const float* bw  = (const float*)d_in[1];
  const int*   qwq = (const int*)d_in[2];
  const int*   qwk = (const int*)d_in[3];
  const int*   qwv = (const int*)d_in[4];
  const int*   qzq = (const int*)d_in[5];
  const int*   qzk = (const int*)d_in[6];
  const int*   qzv = (const int*)d_in[7];
  const float* scq = (const float*)d_in[8];
  const float* sck = (const float*)d_in[9];
  const float* scv = (const float*)d_in[10];
  const int*   idx = (const int*)d_in[11];
  float* out = (float*)d_out;

  // workspace layout (needs ~235 MB)
  char* ws = (char*)d_ws;
  short* xb = (short*)ws;                                       // 33,554,432 B
  short* wc = (short*)(ws + (size_t)33554432);                  // 201,326,592 B
  int* token_list = (int*)(ws + (size_t)33554432 + 201326592);  // 16,384 B
  int* grp = token_list + TOKENS;                               // 256 B

  prep_tokens<<<1, 256, 0, stream>>>(idx, token_list, grp);
  cvt_x<<<(TOKENS * HIDDEN) / (256 * 8), 256, 0, stream>>>(x, xb);
  dim3 gc(HIDDEN / 64, NTOT / 64);  // (64, 96)
  combine_w<<<gc, 256, 0, stream>>>(bw, qwq, qwk, qwv, qzq, qzk, qzv, scq, sck, scv, wc);
  dim3 gg(NTOT / 256, MAXTILES);  // (24, 20)
  gemm_grouped<<<gg, 512, 0, stream>>>(xb, wc, token_list, grp, out);
}